// Round 1
// baseline (2923.870 us; speedup 1.0000x reference)
//
#include <hip/hip_runtime.h>
#include <hip/hip_bf16.h>
#include <math.h>

#define EPS   1e-6f
#define NDIM  8192
#define NSTEPS 50
// exp(-C/gamma) = exp2(C * SCALE), SCALE = -log2(e)/0.1
#define SCALE (-14.426950408889634f)

__device__ __forceinline__ float bf16lo(unsigned u) { return __uint_as_float(u << 16); }
__device__ __forceinline__ float bf16hi(unsigned u) { return __uint_as_float(u & 0xffff0000u); }

// pack two fp32 -> two bf16 (RNE), a in low 16, b in high 16
__device__ __forceinline__ unsigned pack2bf16(float a, float b) {
  unsigned ua = __float_as_uint(a), ub = __float_as_uint(b);
  ua = (ua + 0x7fffu + ((ua >> 16) & 1u)) >> 16;
  ub = (ub + 0x7fffu + ((ub >> 16) & 1u)) & 0xffff0000u;
  return ua | ub;
}

// ---- Prologue: K = bf16(exp(-C/gamma)), 8 elems/thread -------------------
__global__ __launch_bounds__(1024) void prologue_k(const float4* __restrict__ C,
                                                   uint4* __restrict__ K) {
  int tid = blockIdx.x * 1024 + threadIdx.x;   // 8192 blocks -> 8,388,608 threads
  float4 c0 = C[tid * 2], c1 = C[tid * 2 + 1];
  uint4 o;
  o.x = pack2bf16(exp2f(c0.x * SCALE), exp2f(c0.y * SCALE));
  o.y = pack2bf16(exp2f(c0.z * SCALE), exp2f(c0.w * SCALE));
  o.z = pack2bf16(exp2f(c1.x * SCALE), exp2f(c1.y * SCALE));
  o.w = pack2bf16(exp2f(c1.z * SCALE), exp2f(c1.w * SCALE));
  K[tid] = o;
}

// ---- Phase A: y = K b (row GEMV); a = (d+eps)/y; also zero zcur ----------
// 256 blocks x 1024 threads; block handles 32 rows, one row per wave.
template <bool USEK>
__global__ __launch_bounds__(1024) void phaseA_k(const void* __restrict__ Kp,
                                                 const float* __restrict__ zprev,
                                                 const float* __restrict__ s,
                                                 const float* __restrict__ d,
                                                 float* __restrict__ a,
                                                 float* __restrict__ zcur) {
  __shared__ float bs[NDIM];
  int t = threadIdx.x;
  // fill b into LDS: b_j = (s_j+eps)/zprev_j, or e (v0 = ones) on iter 0
  float4* bs4 = (float4*)bs;
  if (zprev) {
    const float4* zp4 = (const float4*)zprev;
    const float4* s4 = (const float4*)s;
    float4 za = zp4[2 * t], zb = zp4[2 * t + 1];
    float4 sa = s4[2 * t], sb = s4[2 * t + 1];
    float4 ba, bb;
    ba.x = (sa.x + EPS) / za.x; ba.y = (sa.y + EPS) / za.y;
    ba.z = (sa.z + EPS) / za.z; ba.w = (sa.w + EPS) / za.w;
    bb.x = (sb.x + EPS) / zb.x; bb.y = (sb.y + EPS) / zb.y;
    bb.z = (sb.z + EPS) / zb.z; bb.w = (sb.w + EPS) / zb.w;
    bs4[2 * t] = ba; bs4[2 * t + 1] = bb;
  } else {
    const float E = 2.718281828459045f;
    float4 e4 = {E, E, E, E};
    bs4[2 * t] = e4; bs4[2 * t + 1] = e4;
  }
  // zero this block's chunk of zcur (consumed by phase B atomics later)
  if (t < 32) zcur[blockIdx.x * 32 + t] = 0.f;
  __syncthreads();

  int wave = t >> 6, lane = t & 63;
  for (int rr = wave; rr < 32; rr += 16) {
    int row = blockIdx.x * 32 + rr;
    float acc = 0.f;
    if (USEK) {
      const uint4* Kq = (const uint4*)Kp + row * 1024;  // 1024 uint4 per row
      #pragma unroll 4
      for (int k = 0; k < 16; k++) {
        int idx = k * 64 + lane;
        uint4 q = Kq[idx];
        const float4* bp = (const float4*)&bs[idx * 8];
        float4 b0 = bp[0], b1 = bp[1];
        acc += bf16lo(q.x) * b0.x + bf16hi(q.x) * b0.y
             + bf16lo(q.y) * b0.z + bf16hi(q.y) * b0.w
             + bf16lo(q.z) * b1.x + bf16hi(q.z) * b1.y
             + bf16lo(q.w) * b1.z + bf16hi(q.w) * b1.w;
      }
    } else {
      const float4* Cq = (const float4*)Kp + row * 2048;
      for (int k = 0; k < 16; k++) {
        int idx = k * 64 + lane;
        float4 c0 = Cq[idx * 2], c1 = Cq[idx * 2 + 1];
        const float4* bp = (const float4*)&bs[idx * 8];
        float4 b0 = bp[0], b1 = bp[1];
        acc += exp2f(c0.x * SCALE) * b0.x + exp2f(c0.y * SCALE) * b0.y
             + exp2f(c0.z * SCALE) * b0.z + exp2f(c0.w * SCALE) * b0.w
             + exp2f(c1.x * SCALE) * b1.x + exp2f(c1.y * SCALE) * b1.y
             + exp2f(c1.z * SCALE) * b1.z + exp2f(c1.w * SCALE) * b1.w;
      }
    }
    #pragma unroll
    for (int off = 32; off; off >>= 1) acc += __shfl_down(acc, off, 64);
    if (lane == 0) a[row] = (d[row] + EPS) / acc;
  }
}

// ---- Phase B: z = K^T a (col GEMV), atomic accumulate into zcur ----------
// 256 blocks = 8 col-groups (1024 cols) x 32 row-groups (256 rows).
// Threads: 128 col-threads (8 cols each) x 8 row-lanes (32 rows each).
template <bool USEK>
__global__ __launch_bounds__(1024) void phaseB_k(const void* __restrict__ Kp,
                                                 const float* __restrict__ a,
                                                 float* __restrict__ zcur) {
  __shared__ float as_[256];
  __shared__ float part[8 * 1024];
  int t = threadIdx.x;
  int cg = blockIdx.x & 7, rg = blockIdx.x >> 3;
  if (t < 256) as_[t] = a[rg * 256 + t];
  __syncthreads();
  int ct = t & 127, rl = t >> 7;
  float acc[8];
  #pragma unroll
  for (int k = 0; k < 8; k++) acc[k] = 0.f;
  int r0 = rg * 256 + rl * 32;
  if (USEK) {
    const uint4* Kq = (const uint4*)Kp;
    int base = cg * 128 + ct;                 // uint4 index within row
    for (int rr = 0; rr < 32; rr++) {
      int r = r0 + rr;
      uint4 q = Kq[r * 1024 + base];
      float av = as_[rl * 32 + rr];
      acc[0] += bf16lo(q.x) * av; acc[1] += bf16hi(q.x) * av;
      acc[2] += bf16lo(q.y) * av; acc[3] += bf16hi(q.y) * av;
      acc[4] += bf16lo(q.z) * av; acc[5] += bf16hi(q.z) * av;
      acc[6] += bf16lo(q.w) * av; acc[7] += bf16hi(q.w) * av;
    }
  } else {
    const float4* Cq = (const float4*)Kp;
    int base = cg * 256 + ct * 2;             // float4 index within row
    for (int rr = 0; rr < 32; rr++) {
      int r = r0 + rr;
      float4 c0 = Cq[r * 2048 + base], c1 = Cq[r * 2048 + base + 1];
      float av = as_[rl * 32 + rr];
      acc[0] += exp2f(c0.x * SCALE) * av; acc[1] += exp2f(c0.y * SCALE) * av;
      acc[2] += exp2f(c0.z * SCALE) * av; acc[3] += exp2f(c0.w * SCALE) * av;
      acc[4] += exp2f(c1.x * SCALE) * av; acc[5] += exp2f(c1.y * SCALE) * av;
      acc[6] += exp2f(c1.z * SCALE) * av; acc[7] += exp2f(c1.w * SCALE) * av;
    }
  }
  float* pp = &part[rl * 1024 + ct * 8];
  #pragma unroll
  for (int k = 0; k < 8; k++) pp[k] = acc[k];
  __syncthreads();
  float sum = 0.f;
  #pragma unroll
  for (int r2 = 0; r2 < 8; r2++) sum += part[r2 * 1024 + t];
  atomicAdd(&zcur[cg * 1024 + t], sum);      // 32 adds per address
}

// ---- Epilogue: P = a_i * exp(-C/gamma) * b_j (fp32 C for precision) ------
__global__ __launch_bounds__(1024) void epilogue_k(const float4* __restrict__ C,
                                                   const float* __restrict__ a,
                                                   const float* __restrict__ zlast,
                                                   const float* __restrict__ s,
                                                   float4* __restrict__ out) {
  __shared__ float bs[NDIM];
  int t = threadIdx.x;
  #pragma unroll
  for (int k = 0; k < 8; k++) {
    int j = t * 8 + k;
    bs[j] = (s[j] + EPS) / zlast[j];
  }
  __syncthreads();
  int wave = t >> 6, lane = t & 63;
  for (int rr = wave; rr < 32; rr += 16) {
    int row = blockIdx.x * 32 + rr;
    float av = a[row];
    const float4* Crow = C + row * 2048;
    float4* Orow = out + row * 2048;
    for (int k = 0; k < 32; k++) {
      int idx = k * 64 + lane;
      float4 c = Crow[idx];
      float4 p;
      p.x = av * bs[idx * 4 + 0] * exp2f(c.x * SCALE);
      p.y = av * bs[idx * 4 + 1] * exp2f(c.y * SCALE);
      p.z = av * bs[idx * 4 + 2] * exp2f(c.z * SCALE);
      p.w = av * bs[idx * 4 + 3] * exp2f(c.w * SCALE);
      Orow[idx] = p;
    }
  }
}

extern "C" void kernel_launch(void* const* d_in, const int* in_sizes, int n_in,
                              void* d_out, int out_size, void* d_ws, size_t ws_size,
                              hipStream_t stream) {
  const float* C = (const float*)d_in[0];
  const float* d = (const float*)d_in[1];
  const float* s = (const float*)d_in[2];

  float* z0 = (float*)d_ws;
  float* z1 = z0 + NDIM;
  float* a  = z1 + NDIM;
  char* kbase = (char*)d_ws + 131072;
  size_t kneed = 131072 + (size_t)NDIM * NDIM * 2;  // vectors + bf16 K
  bool usek = ws_size >= kneed;

  if (usek) {
    prologue_k<<<8192, 1024, 0, stream>>>((const float4*)C, (uint4*)kbase);
  }
  const void* Kp = usek ? (const void*)kbase : (const void*)C;

  for (int it = 0; it < NSTEPS; ++it) {
    float* zc = (it & 1) ? z1 : z0;
    const float* zp = (it == 0) ? nullptr : ((it & 1) ? z0 : z1);
    if (usek) {
      phaseA_k<true><<<256, 1024, 0, stream>>>(Kp, zp, s, d, a, zc);
      phaseB_k<true><<<256, 1024, 0, stream>>>(Kp, a, zc);
    } else {
      phaseA_k<false><<<256, 1024, 0, stream>>>(Kp, zp, s, d, a, zc);
      phaseB_k<false><<<256, 1024, 0, stream>>>(Kp, a, zc);
    }
  }
  const float* zlast = ((NSTEPS - 1) & 1) ? z1 : z0;
  epilogue_k<<<256, 1024, 0, stream>>>((const float4*)C, a, zlast, s, (float4*)d_out);
}